// Round 22
// baseline (1719.440 us; speedup 1.0000x reference)
//
#include <hip/hip_runtime.h>
#include <math.h>

#define HID 51
#define TMAIN 1024
#define FUT 64
#define TT (TMAIN + FUT)
#define RING 128  // h2 history ring depth (pow2)
#define RPAD 68   // h2 ring row stride in floats (272B, 16B-aligned)

typedef float v2f __attribute__((ext_vector_type(2)));

__device__ __forceinline__ float fast_sigmoid(float x) {
  return 1.0f / (1.0f + __expf(-x));
}
__device__ __forceinline__ float fast_tanh(float x) {
  return 1.0f - 2.0f / (__expf(2.0f * x) + 1.0f);
}

// One-row dual-seq dot: a{A,B} += sum_k w_row[k] * h{A,B}[k], k=0..50.
// w packed as 26 v2f (pair 25 = {w50, 0}); h read as 13 float4 (broadcast,
// uniform address); h[51] must be 0. Two chains per seq hide FMA latency.
__device__ __forceinline__ void dotRow(const float* hA, const float* hB,
                                       const v2f (&w)[26], float& aA,
                                       float& aB) {
  const float4* a4 = reinterpret_cast<const float4*>(hA);
  const float4* b4 = reinterpret_cast<const float4*>(hB);
  v2f sA0 = {0.f, 0.f}, sA1 = {0.f, 0.f};
  v2f sB0 = {0.f, 0.f}, sB1 = {0.f, 0.f};
#pragma unroll
  for (int q = 0; q < 7; ++q) {
    float4 ha = a4[q], hb = b4[q];
    v2f alo = {ha.x, ha.y}, ahi = {ha.z, ha.w};
    v2f blo = {hb.x, hb.y}, bhi = {hb.z, hb.w};
    sA0 = __builtin_elementwise_fma(alo, w[2 * q + 0], sA0);
    sB0 = __builtin_elementwise_fma(blo, w[2 * q + 0], sB0);
    sA0 = __builtin_elementwise_fma(ahi, w[2 * q + 1], sA0);
    sB0 = __builtin_elementwise_fma(bhi, w[2 * q + 1], sB0);
  }
#pragma unroll
  for (int q = 7; q < 13; ++q) {
    float4 ha = a4[q], hb = b4[q];
    v2f alo = {ha.x, ha.y}, ahi = {ha.z, ha.w};
    v2f blo = {hb.x, hb.y}, bhi = {hb.z, hb.w};
    sA1 = __builtin_elementwise_fma(alo, w[2 * q + 0], sA1);
    sB1 = __builtin_elementwise_fma(blo, w[2 * q + 0], sB1);
    sA1 = __builtin_elementwise_fma(ahi, w[2 * q + 1], sA1);
    sB1 = __builtin_elementwise_fma(bhi, w[2 * q + 1], sB1);
  }
  aA += (sA0.x + sA0.y) + (sA1.x + sA1.y);
  aB += (sB0.x + sB0.y) + (sB1.x + sB1.y);
}

// Intra-quad gate recombine + LSTM cell. Lane's gate = g; a = this lane's
// pre-activation. b1/b2/b3 = shfl_xor(a, 1/2/3) (gate g^1, g^2, g^3).
// Gate j's value = [a,b1,b2,b3][j^g]. All 4 quad lanes compute identically.
__device__ __forceinline__ float quad_cell(int g, float a, float b1, float b2,
                                           float b3, float& c) {
  float vi = (g == 0) ? a : ((g == 1) ? b1 : ((g == 2) ? b2 : b3));
  float vf = (g == 1) ? a : ((g == 0) ? b1 : ((g == 3) ? b2 : b3));
  float vg = (g == 2) ? a : ((g == 3) ? b1 : ((g == 0) ? b2 : b3));
  float vo = (g == 3) ? a : ((g == 2) ? b1 : ((g == 1) ? b2 : b3));
  c = fast_sigmoid(vf) * c + fast_sigmoid(vi) * fast_tanh(vg);
  return fast_sigmoid(vo) * fast_tanh(c);
}

// One block = TWO sequences, 12 waves, GATE-PER-LANE-QUAD decomposition.
// R21 lessons: (a) soft-cap kernels park overflow regs in AGPRs (invisible
// to VGPR_Count) -> total >128/wave -> occupancy pinned at 1 block/CU;
// (b) per-step time scales ~linearly with per-wave work (single-seq 102-MAC
// waves: 1707 cy/step vs dual-seq 204-MAC: 3265). So this round halves
// per-wave work again WITHOUT the 2-pass penalty: lane = (unit-quad, gate)
// holds ONE 51-float weight row (~85 total regs, genuinely <=128):
//   waves 0-3:  L1 cell, 13 units each (w3: 12); lane g in {i,f,g,o}
//   waves 4-7:  L2 cell (carry c2, wlin; lin-head butterfly in feedback)
//   waves 8-11: Wi2 full-row -> piK (one piece); w8/w10 run the deferred
//               lin-head flush for seq0/seq1
// Gate recombine: 3 intra-quad shfl_xor + selects; 4 lanes redundant cell.
// Pipeline (1 barrier/step): h1(k) | piK(k-1) | h2(k-2); h2 in 128-ring;
// flush every 64 steps; feedback = 3-sub-phase barriered.
// piK stride 65 spreads the 4 gate banks (quad writes hit 4 banks).
__global__ __launch_bounds__(768, 3)
void lstm2_persistent(const float* __restrict__ input,
                      const float* __restrict__ Wi1,
                      const float* __restrict__ Wh1,
                      const float* __restrict__ bi1,
                      const float* __restrict__ bh1,
                      const float* __restrict__ Wi2,
                      const float* __restrict__ Wh2,
                      const float* __restrict__ bi2,
                      const float* __restrict__ bh2,
                      const float* __restrict__ Wlin,
                      const float* __restrict__ blin,
                      float* __restrict__ out) {
  __shared__ __align__(16) float lds_x[2][TMAIN];        // 8 KB
  __shared__ __align__(16) float lds_h1[2][2][64];       // [par][seq][u] 2 KB
  __shared__ __align__(16) float lds_piK[2][2][4][65];   // [par][seq][g][u]
  __shared__ __align__(16) float lds_h2h[2][RING][RPAD]; // 69.6 KB
  __shared__ __align__(16) float lds_wlin[64];
  __shared__ __align__(16) float lds_outbuf[2][64];      // feedback outputs
  __shared__ float lds_lin[2][2][4];                     // [par][seq][L2wave]
  __shared__ float lds_fb[2];                            // out(1023) seed

  const int tid = threadIdx.x;
  const int s0 = blockIdx.x * 2;  // sequence pair
  const int wid = tid >> 6;       // 0..11
  const int lane = tid & 63;
  const int q = lane >> 2;   // quad index 0..15
  const int g = lane & 3;    // gate {i,f,g,o}
  const int rw = (wid < 4) ? wid : ((wid < 8) ? wid - 4 : wid - 8);
  const int nu = (rw < 3) ? 13 : 12;  // units per wave (51 = 13+13+13+12)
  const bool act = q < nu;
  const int u = 13 * rw + (act ? q : (nu - 1));  // clamped unit

  // ---- staging ----
  for (int i = tid; i < TMAIN; i += 768) {
    lds_x[0][i] = input[s0 * TMAIN + i];
    lds_x[1][i] = input[(s0 + 1) * TMAIN + i];
  }
  for (int i = tid; i < 2 * 2 * 64; i += 768)
    (&lds_h1[0][0][0])[i] = 0.0f;  // elems 51..63 stay 0 forever
  for (int i = tid; i < 2 * RING * RPAD; i += 768)
    (&lds_h2h[0][0][0])[i] = 0.0f;  // element 51 stays 0 forever
  if (tid < 64) lds_wlin[tid] = (tid < HID) ? Wlin[tid] : 0.0f;

  // ---- per-lane weight row (ONE row of 51 -> 26 v2f pairs) ----
  v2f w[26];
  float bias = 0.0f;    // cells: bi+bh for (g,u)
  float wi1g = 0.0f;    // L1: Wi1[g*HID+u]
  float wlin_u = 0.0f;  // L2: Wlin[u]
  float cA = 0.0f, cB = 0.0f;  // redundant per-quad cell states

  {
    const float* Wsel = (wid < 4) ? Wh1 : ((wid < 8) ? Wh2 : Wi2);
    const float* row = Wsel + (g * HID + u) * HID;
#pragma unroll
    for (int p = 0; p < 25; ++p) {
      v2f t;
      t.x = row[2 * p + 0];
      t.y = row[2 * p + 1];
      w[p] = t;
    }
    v2f t;
    t.x = row[50];
    t.y = 0.0f;  // pairs with h[51] == 0
    w[25] = t;
  }
  if (wid < 4) {
    bias = bi1[g * HID + u] + bh1[g * HID + u];
    wi1g = Wi1[g * HID + u];
  } else if (wid < 8) {
    bias = bi2[g * HID + u] + bh2[g * HID + u];
    wlin_u = Wlin[u];
  }
#pragma unroll
  for (int p = 0; p < 26; ++p) asm volatile("" : "+v"(w[p]));
  asm volatile("" : "+v"(bias), "+v"(wi1g), "+v"(wlin_u));
  const float blin_s = blin[0];

  __syncthreads();

  // =============== main-phase pipeline: one barrier per step ===========
  for (int k = 0; k <= TMAIN + 2; ++k) {
    if (wid < 4) {
      if (k < TMAIN) {
        // h1(k) = cell1(x(k), h1(k-1)); h1(m) lives in buffer (m+1)&1
        float xA = lds_x[0][k], xB = lds_x[1][k];
        float aA = fmaf(xA, wi1g, bias);
        float aB = fmaf(xB, wi1g, bias);
        dotRow(lds_h1[k & 1][0], lds_h1[k & 1][1], w, aA, aB);
        float a1A = __shfl_xor(aA, 1), a2A = __shfl_xor(aA, 2),
              a3A = __shfl_xor(aA, 3);
        float a1B = __shfl_xor(aB, 1), a2B = __shfl_xor(aB, 2),
              a3B = __shfl_xor(aB, 3);
        float hA = quad_cell(g, aA, a1A, a2A, a3A, cA);
        float hB = quad_cell(g, aB, a1B, a2B, a3B, cB);
        if (act && g == 0) {
          lds_h1[(k + 1) & 1][0][u] = hA;
          lds_h1[(k + 1) & 1][1][u] = hB;
        }
      }
    } else if (wid < 8) {
      if (k >= 2 && k <= TMAIN + 1) {
        // h2(m2) = cell2(bias + piK(m2) + Wh2 @ h2(m2-1))
        const int m2 = k - 2;
        const int pm = m2 & 1;
        float aA = bias + lds_piK[pm][0][g][u];
        float aB = bias + lds_piK[pm][1][g][u];
        dotRow(&lds_h2h[0][(m2 - 1) & (RING - 1)][0],
               &lds_h2h[1][(m2 - 1) & (RING - 1)][0], w, aA, aB);
        float a1A = __shfl_xor(aA, 1), a2A = __shfl_xor(aA, 2),
              a3A = __shfl_xor(aA, 3);
        float a1B = __shfl_xor(aB, 1), a2B = __shfl_xor(aB, 2),
              a3B = __shfl_xor(aB, 3);
        float hA = quad_cell(g, aA, a1A, a2A, a3A, cA);
        float hB = quad_cell(g, aB, a1B, a2B, a3B, cB);
        if (act && g == 0) {
          lds_h2h[0][m2 & (RING - 1)][u] = hA;
          lds_h2h[1][m2 & (RING - 1)][u] = hB;
        }
      }
    } else {
      if (k >= 1 && k <= TMAIN) {
        // piK(k-1) = Wi2 row dot h1(k-1) (h1(k-1) in buffer k&1)
        float aA = 0.0f, aB = 0.0f;
        dotRow(lds_h1[k & 1][0], lds_h1[k & 1][1], w, aA, aB);
        const int pm = (k - 1) & 1;
        if (act) {
          lds_piK[pm][0][g][u] = aA;
          lds_piK[pm][1][g][u] = aB;
        }
      }
      // Deferred linear head: every 64 steps, w8 (seq0) / w10 (seq1) emit
      // 64 outputs (chunk c=k-66; h2(c+63) landed at step c+65; writer
      // this step touches slot (c+64)&127 -- disjoint from read slots).
      if ((wid == 8 || wid == 10) && k >= 66 && ((k - 66) & 63) == 0) {
        const int seq = (wid - 8) >> 1;
        const int c = k - 66;
        const int m = c + lane;
        const float* r = &lds_h2h[seq][m & (RING - 1)][0];
        const float4* r4 = reinterpret_cast<const float4*>(r);
        const float4* w4 = reinterpret_cast<const float4*>(lds_wlin);
        float o0 = 0.f, o1 = 0.f, o2 = 0.f, o3 = 0.f;
#pragma unroll
        for (int qq = 0; qq < 13; ++qq) {  // r[51]=0, wlin[51]=0
          float4 rv = r4[qq];
          float4 wv = w4[qq];
          o0 = fmaf(rv.x, wv.x, o0);
          o1 = fmaf(rv.y, wv.y, o1);
          o2 = fmaf(rv.z, wv.z, o2);
          o3 = fmaf(rv.w, wv.w, o3);
        }
        float o = (o0 + o1) + (o2 + o3) + blin_s;
        out[(s0 + seq) * TT + m] = o;
        if (m == TMAIN - 1) lds_fb[seq] = o;  // feedback seed
      }
    }
    __syncthreads();
  }

  // =============== feedback phase: 3 sub-phases, barriered ==============
  for (int t = TMAIN; t < TT; ++t) {
    float phA = 0.0f, phB = 0.0f;
    // --- A: L1 cells with feedback x; L2 waves pre-dot Wh2 @ h2(t-1) ---
    if (wid < 4) {
      float oA, oB;
      if (t == TMAIN) {
        oA = lds_fb[0];
        oB = lds_fb[1];
      } else {
        const int p = (t - 1) & 1;
        oA = lds_lin[p][0][0] + lds_lin[p][0][1] + lds_lin[p][0][2] +
             lds_lin[p][0][3] + blin_s;
        oB = lds_lin[p][1][0] + lds_lin[p][1][1] + lds_lin[p][1][2] +
             lds_lin[p][1][3] + blin_s;
        if (wid == 0 && lane == 0) {
          lds_outbuf[0][t - 1 - TMAIN] = oA;
          lds_outbuf[1][t - 1 - TMAIN] = oB;
        }
      }
      float aA = fmaf(oA, wi1g, bias);
      float aB = fmaf(oB, wi1g, bias);
      dotRow(lds_h1[t & 1][0], lds_h1[t & 1][1], w, aA, aB);
      float a1A = __shfl_xor(aA, 1), a2A = __shfl_xor(aA, 2),
            a3A = __shfl_xor(aA, 3);
      float a1B = __shfl_xor(aB, 1), a2B = __shfl_xor(aB, 2),
            a3B = __shfl_xor(aB, 3);
      float hA = quad_cell(g, aA, a1A, a2A, a3A, cA);
      float hB = quad_cell(g, aB, a1B, a2B, a3B, cB);
      if (act && g == 0) {
        lds_h1[(t + 1) & 1][0][u] = hA;
        lds_h1[(t + 1) & 1][1][u] = hB;
      }
    } else if (wid < 8) {
      dotRow(&lds_h2h[0][(t - 1) & (RING - 1)][0],
             &lds_h2h[1][(t - 1) & (RING - 1)][0], w, phA, phB);
    }
    __syncthreads();
    // --- B: Wi2 rows from h1(t) ---
    if (wid >= 8) {
      float aA = 0.0f, aB = 0.0f;
      dotRow(lds_h1[(t + 1) & 1][0], lds_h1[(t + 1) & 1][1], w, aA, aB);
      const int pm = t & 1;
      if (act) {
        lds_piK[pm][0][g][u] = aA;
        lds_piK[pm][1][g][u] = aB;
      }
    }
    __syncthreads();
    // --- C: L2 cells + linear head (per-wave butterfly, 4 partials) ---
    if (wid >= 4 && wid < 8) {
      const int pm = t & 1;
      float aA = bias + lds_piK[pm][0][g][u] + phA;
      float aB = bias + lds_piK[pm][1][g][u] + phB;
      float a1A = __shfl_xor(aA, 1), a2A = __shfl_xor(aA, 2),
            a3A = __shfl_xor(aA, 3);
      float a1B = __shfl_xor(aB, 1), a2B = __shfl_xor(aB, 2),
            a3B = __shfl_xor(aB, 3);
      float hA = quad_cell(g, aA, a1A, a2A, a3A, cA);
      float hB = quad_cell(g, aB, a1B, a2B, a3B, cB);
      float valA = 0.0f, valB = 0.0f;
      if (act && g == 0) {
        lds_h2h[0][t & (RING - 1)][u] = hA;
        lds_h2h[1][t & (RING - 1)][u] = hB;
        valA = wlin_u * hA;
        valB = wlin_u * hB;
      }
#pragma unroll
      for (int off = 32; off >= 1; off >>= 1) {
        valA += __shfl_xor(valA, off);
        valB += __shfl_xor(valB, off);
      }
      if (lane == 0) {
        lds_lin[t & 1][0][rw] = valA;
        lds_lin[t & 1][1][rw] = valB;
      }
    }
    __syncthreads();
  }

  // epilogue: buffer out(TT-1), then flush the 64 future outputs
  if (wid == 0 && lane == 0) {
    const int p = (TT - 1) & 1;
    lds_outbuf[0][63] = lds_lin[p][0][0] + lds_lin[p][0][1] +
                        lds_lin[p][0][2] + lds_lin[p][0][3] + blin_s;
    lds_outbuf[1][63] = lds_lin[p][1][0] + lds_lin[p][1][1] +
                        lds_lin[p][1][2] + lds_lin[p][1][3] + blin_s;
  }
  __syncthreads();
  if (wid == 8 || wid == 10) {
    const int seq = (wid - 8) >> 1;
    out[(s0 + seq) * TT + TMAIN + lane] = lds_outbuf[seq][lane];
  }
}

extern "C" void kernel_launch(void* const* d_in, const int* in_sizes, int n_in,
                              void* d_out, int out_size, void* d_ws,
                              size_t ws_size, hipStream_t stream) {
  const float* input = (const float*)d_in[0];
  const float* Wi1 = (const float*)d_in[1];
  const float* Wh1 = (const float*)d_in[2];
  const float* bi1 = (const float*)d_in[3];
  const float* bh1 = (const float*)d_in[4];
  const float* Wi2 = (const float*)d_in[5];
  const float* Wh2 = (const float*)d_in[6];
  const float* bi2 = (const float*)d_in[7];
  const float* bh2 = (const float*)d_in[8];
  const float* Wlin = (const float*)d_in[9];
  const float* blin = (const float*)d_in[10];
  float* out = (float*)d_out;

  const int B = in_sizes[0] / TMAIN;  // 512
  lstm2_persistent<<<B / 2, 768, 0, stream>>>(input, Wi1, Wh1, bi1, bh1, Wi2,
                                              Wh2, bi2, bh2, Wlin, blin, out);
}

// Round 23
// 1361.131 us; speedup vs baseline: 1.2632x; 1.2632x over previous
//
#include <hip/hip_runtime.h>
#include <math.h>

#define HID 51
#define TMAIN 1024
#define FUT 64
#define TT (TMAIN + FUT)
#define RING 128   // h2 history ring depth (pow2)
#define RPAD 68    // ring row stride in floats (16B-aligned, bank-skewed)

typedef float v2f __attribute__((ext_vector_type(2)));

__device__ __forceinline__ float fast_sigmoid(float x) {
  return 1.0f / (1.0f + __expf(-x));
}
__device__ __forceinline__ float fast_tanh(float x) {
  return 1.0f - 2.0f / (__expf(2.0f * x) + 1.0f);
}

// Dual-sequence packed full-K dot: acc{A,B}[g] += sum_k w[g][k]*h{A,B}[k].
// float4 LDS reads; a4[12] touches h[48..51] (element 51 loaded but unused).
__device__ __forceinline__ void dot2x(const float* hA, const float* hB,
                                      const v2f (&w2)[2][25],
                                      const float (&w50)[2],
                                      float (&aA)[2], float (&aB)[2]) {
  const float4* a4 = reinterpret_cast<const float4*>(hA);
  const float4* b4 = reinterpret_cast<const float4*>(hB);
  v2f sA0 = {0.f, 0.f}, sA1 = {0.f, 0.f};
  v2f sB0 = {0.f, 0.f}, sB1 = {0.f, 0.f};
#pragma unroll
  for (int q = 0; q < 12; ++q) {
    float4 av = a4[q];
    float4 bv = b4[q];
    v2f alo = {av.x, av.y}, ahi = {av.z, av.w};
    v2f blo = {bv.x, bv.y}, bhi = {bv.z, bv.w};
    sA0 = __builtin_elementwise_fma(alo, w2[0][2 * q + 0], sA0);
    sB0 = __builtin_elementwise_fma(blo, w2[0][2 * q + 0], sB0);
    sA1 = __builtin_elementwise_fma(alo, w2[1][2 * q + 0], sA1);
    sB1 = __builtin_elementwise_fma(blo, w2[1][2 * q + 0], sB1);
    sA0 = __builtin_elementwise_fma(ahi, w2[0][2 * q + 1], sA0);
    sB0 = __builtin_elementwise_fma(bhi, w2[0][2 * q + 1], sB0);
    sA1 = __builtin_elementwise_fma(ahi, w2[1][2 * q + 1], sA1);
    sB1 = __builtin_elementwise_fma(bhi, w2[1][2 * q + 1], sB1);
  }
  float4 at = a4[12];
  float4 bt = b4[12];
  v2f alo = {at.x, at.y}, blo = {bt.x, bt.y};
  sA0 = __builtin_elementwise_fma(alo, w2[0][24], sA0);
  sB0 = __builtin_elementwise_fma(blo, w2[0][24], sB0);
  sA1 = __builtin_elementwise_fma(alo, w2[1][24], sA1);
  sB1 = __builtin_elementwise_fma(blo, w2[1][24], sB1);
  aA[0] = fmaf(at.z, w50[0], aA[0] + sA0.x + sA0.y);
  aB[0] = fmaf(bt.z, w50[0], aB[0] + sB0.x + sB0.y);
  aA[1] = fmaf(at.z, w50[1], aA[1] + sA1.x + sA1.y);
  aB[1] = fmaf(bt.z, w50[1], aB[1] + sB1.x + sB1.y);
}

// Half-K dual-seq dot: 13 float2 pairs starting at a pre-offset pointer.
// K2 waves' pair 12 multiplies {h[50],h[51]} by {w50,0}; h1[51] is kept 0.
__device__ __forceinline__ void dotH(const float* hA, const float* hB,
                                     const v2f (&w)[2][13],
                                     float (&aA)[2], float (&aB)[2]) {
  const float2* a2 = reinterpret_cast<const float2*>(hA);
  const float2* b2 = reinterpret_cast<const float2*>(hB);
  v2f sA0 = {0.f, 0.f}, sA1 = {0.f, 0.f};
  v2f sB0 = {0.f, 0.f}, sB1 = {0.f, 0.f};
#pragma unroll
  for (int p = 0; p < 13; ++p) {
    float2 av = a2[p], bv = b2[p];
    v2f a = {av.x, av.y}, b = {bv.x, bv.y};
    sA0 = __builtin_elementwise_fma(a, w[0][p], sA0);
    sB0 = __builtin_elementwise_fma(b, w[0][p], sB0);
    sA1 = __builtin_elementwise_fma(a, w[1][p], sA1);
    sB1 = __builtin_elementwise_fma(b, w[1][p], sB1);
  }
  aA[0] = sA0.x + sA0.y;
  aB[0] = sB0.x + sB0.y;
  aA[1] = sA1.x + sA1.y;
  aB[1] = sB1.x + sB1.y;
}

// One block = TWO sequences, 8 waves (FINAL best-known configuration;
// benched 1360.5 us in R18, 2.19x over the 2980 us session baseline):
//   wid0,1: L1 cell, units [0,26)/[26,51)
//   wid2,3: Wh2 cell (L2), units [0,26)/[26,51)   [carry c2; feedback lin]
//   wid4,5: Wi2 K[26,51) partial (+bias2 fold)    [+ main-phase out flush]
//   wid6,7: Wi2 K[0,26)  partial -> piK1
// Pipeline skew (1 barrier/interval): h1(k) | piK(k-1) | h2(k-2).
// Linear head OUT of the loop: h2 history in a 128-ring; every 64
// intervals waves 4,5 compute+store 64 outputs each (plain 51-FMA dots).
// Feedback phase (out->x serial) runs a 3-sub-phase barriered schedule.
// Session ledger (13 alternatives tied or regressed vs this):
//  - piS float4 gather: null (+29M bank conflicts); LDS flag sync: +19%;
//  - wave-local cells: spill wall at ~128 arch VGPRs (5 data points;
//    overflow parks in AGPRs under soft caps -> occupancy stuck 1 blk/CU,
//    hard caps -> allocator cap-collapse to scratch);
//  - 4-step barrier intervals / streamed gates: +43-50%;
//  - single-seq 2-pass: +14%; gate-per-lane quads: +26% (2x LDS/MAC).
// => latency floor ~3.25k cy/step for this dependency graph.
__global__ __launch_bounds__(512, 2)
void lstm2_persistent(const float* __restrict__ input,
                      const float* __restrict__ Wi1,
                      const float* __restrict__ Wh1,
                      const float* __restrict__ bi1,
                      const float* __restrict__ bh1,
                      const float* __restrict__ Wi2,
                      const float* __restrict__ Wh2,
                      const float* __restrict__ bi2,
                      const float* __restrict__ bh2,
                      const float* __restrict__ Wlin,
                      const float* __restrict__ blin,
                      float* __restrict__ out) {
  __shared__ __align__(16) float lds_x[2][TMAIN];          // [seq][t]
  __shared__ __align__(16) float lds_h1[2][2][64];         // [seq][parity][u]
  __shared__ __align__(16) float lds_piK1[2][2][4][64];    // [par][seq][g][u]
  __shared__ __align__(16) float lds_piK2[2][2][4][64];    // [par][seq][g][u]
  __shared__ __align__(16) float lds_h2h[2][RING][RPAD];   // h2 history ring
  __shared__ __align__(16) float lds_wlin[64];
  __shared__ __align__(16) float lds_outbuf[2][64];        // feedback outputs
  __shared__ float lds_lin[2][2][2];                       // [par][seq][cellw]
  __shared__ float lds_fb[2];                              // out(1023) seed

  const int tid = threadIdx.x;
  const int s0 = blockIdx.x * 2;  // sequence pair
  const int wid = tid >> 6;       // 0..7
  const int lane = tid & 63;
  const int half = lane >> 5;   // 0: gates {i,f}, 1: gates {g,o}
  const int l5 = lane & 31;
  const int base = (wid & 1) * 26;
  const int nu = (wid & 1) ? 25 : 26;
  const bool act = l5 < nu;
  const int u = base + (act ? l5 : 0);  // clamped unit index
  const int g0 = half * 2;
  const int koff = (wid >= 6) ? 0 : 26;  // Wi2 K-half offset

  // Stage inputs; zero h1 buffers (incl. elem 51..63 -> dotH pair-12 safe)
  // and ring slot RING-1 (h2(-1) = 0); stage wlin.
  for (int i = tid; i < TMAIN; i += 512) {
    lds_x[0][i] = input[s0 * TMAIN + i];
    lds_x[1][i] = input[(s0 + 1) * TMAIN + i];
  }
  if (tid < 64) {
    lds_h1[0][0][tid] = 0.0f;
    lds_h1[0][1][tid] = 0.0f;
    lds_h1[1][0][tid] = 0.0f;
    lds_h1[1][1][tid] = 0.0f;
    lds_wlin[tid] = (tid < HID) ? Wlin[tid] : 0.0f;
  }
  if (tid < 128) lds_h2h[tid >> 6][RING - 1][tid & 63] = 0.0f;

  // ---- weights ----
  v2f w2f[2][25];  // full rows (L1 / Wh2 cell waves)
  float w50f[2] = {0.f, 0.f};
  v2f w2h[2][13];  // half rows (Wi2 waves)
  float bias[2] = {0.f, 0.f};
  float wi1g[2] = {0.f, 0.f};
  float wlin_u = 0.0f;
  float cA = 0.0f, cB = 0.0f;  // cell states (L1 in wid01, L2 in wid23)

  if (wid < 4) {
    const float* Wsel = (wid < 2) ? Wh1 : Wh2;
#pragma unroll
    for (int g = 0; g < 2; ++g) {
      const float* row = Wsel + ((g0 + g) * HID + u) * HID;
#pragma unroll
      for (int p = 0; p < 25; ++p) {
        v2f t;
        t.x = row[2 * p + 0];
        t.y = row[2 * p + 1];
        w2f[g][p] = t;
      }
      w50f[g] = row[50];
    }
    if (wid < 2) {
#pragma unroll
      for (int g = 0; g < 2; ++g) {
        bias[g] = bi1[(g0 + g) * HID + u] + bh1[(g0 + g) * HID + u];
        wi1g[g] = Wi1[(g0 + g) * HID + u];
      }
    } else {
      wlin_u = Wlin[u];  // feedback-phase butterfly weight
    }
#pragma unroll
    for (int g = 0; g < 2; ++g) {
#pragma unroll
      for (int p = 0; p < 25; ++p) asm volatile("" : "+v"(w2f[g][p]));
      asm volatile("" : "+v"(w50f[g]), "+v"(bias[g]), "+v"(wi1g[g]));
    }
    asm volatile("" : "+v"(wlin_u));
  } else {
#pragma unroll
    for (int g = 0; g < 2; ++g) {
      const float* row = Wi2 + ((g0 + g) * HID + u) * HID + koff;
      if (koff == 0) {
#pragma unroll
        for (int p = 0; p < 13; ++p) {
          v2f t;
          t.x = row[2 * p + 0];
          t.y = row[2 * p + 1];
          w2h[g][p] = t;
        }
      } else {
#pragma unroll
        for (int p = 0; p < 12; ++p) {
          v2f t;
          t.x = row[2 * p + 0];
          t.y = row[2 * p + 1];
          w2h[g][p] = t;
        }
        v2f t;
        t.x = row[24];  // K=50
        t.y = 0.0f;     // pairs with h1[51] == 0
        w2h[g][12] = t;
      }
    }
    if (koff == 26) {  // K2 waves carry bias2 (folded into their piK writes)
#pragma unroll
      for (int g = 0; g < 2; ++g)
        bias[g] = bi2[(g0 + g) * HID + u] + bh2[(g0 + g) * HID + u];
    }
#pragma unroll
    for (int g = 0; g < 2; ++g) {
#pragma unroll
      for (int p = 0; p < 13; ++p) asm volatile("" : "+v"(w2h[g][p]));
      asm volatile("" : "+v"(bias[g]));
    }
  }
  const float blin_s = blin[0];

  __syncthreads();

  // =============== main-phase pipeline: one barrier per interval ========
  for (int k = 0; k <= TMAIN + 2; ++k) {
    if (wid < 2) {
      if (k < TMAIN) {
        // h1(k) = cell1(x(k), h1(k-1));  h1(m) lives in buffer (m+1)&1
        float xA = lds_x[0][k], xB = lds_x[1][k];
        float aA[2], aB[2];
#pragma unroll
        for (int g = 0; g < 2; ++g) {
          aA[g] = fmaf(xA, wi1g[g], bias[g]);
          aB[g] = fmaf(xB, wi1g[g], bias[g]);
        }
        dot2x(lds_h1[0][k & 1], lds_h1[1][k & 1], w2f, w50f, aA, aB);
        float pA0 = __shfl_xor(aA[0], 32), pA1 = __shfl_xor(aA[1], 32);
        float pB0 = __shfl_xor(aB[0], 32), pB1 = __shfl_xor(aB[1], 32);
        float giA = half ? pA0 : aA[0], gfA = half ? pA1 : aA[1];
        float ggA = half ? aA[0] : pA0, goA = half ? aA[1] : pA1;
        float giB = half ? pB0 : aB[0], gfB = half ? pB1 : aB[1];
        float ggB = half ? aB[0] : pB0, goB = half ? aB[1] : pB1;
        cA = fast_sigmoid(gfA) * cA + fast_sigmoid(giA) * fast_tanh(ggA);
        cB = fast_sigmoid(gfB) * cB + fast_sigmoid(giB) * fast_tanh(ggB);
        float hA = fast_sigmoid(goA) * fast_tanh(cA);
        float hB = fast_sigmoid(goB) * fast_tanh(cB);
        if (act && half == 0) {
          lds_h1[0][(k + 1) & 1][u] = hA;
          lds_h1[1][(k + 1) & 1][u] = hB;
        }
      }
    } else if (wid < 4) {
      if (k >= 2 && k <= TMAIN + 1) {
        // h2(m2) = cell2(bias + piK1(m2)+piK2(m2) + Wh2 @ h2(m2-1))
        const int m2 = k - 2;
        const int pm = m2 & 1;
        float aA[2], aB[2];
        aA[0] = lds_piK1[pm][0][g0 + 0][u] + lds_piK2[pm][0][g0 + 0][u];
        aA[1] = lds_piK1[pm][0][g0 + 1][u] + lds_piK2[pm][0][g0 + 1][u];
        aB[0] = lds_piK1[pm][1][g0 + 0][u] + lds_piK2[pm][1][g0 + 0][u];
        aB[1] = lds_piK1[pm][1][g0 + 1][u] + lds_piK2[pm][1][g0 + 1][u];
        dot2x(&lds_h2h[0][(m2 - 1) & (RING - 1)][0],
              &lds_h2h[1][(m2 - 1) & (RING - 1)][0], w2f, w50f, aA, aB);
        float pA0 = __shfl_xor(aA[0], 32), pA1 = __shfl_xor(aA[1], 32);
        float pB0 = __shfl_xor(aB[0], 32), pB1 = __shfl_xor(aB[1], 32);
        float giA = half ? pA0 : aA[0], gfA = half ? pA1 : aA[1];
        float ggA = half ? aA[0] : pA0, goA = half ? aA[1] : pA1;
        float giB = half ? pB0 : aB[0], gfB = half ? pB1 : aB[1];
        float ggB = half ? aB[0] : pB0, goB = half ? aB[1] : pB1;
        cA = fast_sigmoid(gfA) * cA + fast_sigmoid(giA) * fast_tanh(ggA);
        cB = fast_sigmoid(gfB) * cB + fast_sigmoid(giB) * fast_tanh(ggB);
        float hA = fast_sigmoid(goA) * fast_tanh(cA);
        float hB = fast_sigmoid(goB) * fast_tanh(cB);
        if (act && half == 0) {
          lds_h2h[0][m2 & (RING - 1)][u] = hA;
          lds_h2h[1][m2 & (RING - 1)][u] = hB;
        }
      }
    } else {
      if (k >= 1 && k <= TMAIN) {
        // piK(k-1) partial: Wi2[:, koff:koff+26] @ h1(k-1)[koff:...]
        // (bias2 folded into the K2 waves' partials)
        float aA[2], aB[2];
        dotH(&lds_h1[0][k & 1][koff], &lds_h1[1][k & 1][koff], w2h, aA, aB);
        const int pm = (k - 1) & 1;
        if (act) {
          if (koff == 26) {
            aA[0] += bias[0];
            aA[1] += bias[1];
            aB[0] += bias[0];
            aB[1] += bias[1];
            lds_piK2[pm][0][g0 + 0][u] = aA[0];
            lds_piK2[pm][0][g0 + 1][u] = aA[1];
            lds_piK2[pm][1][g0 + 0][u] = aB[0];
            lds_piK2[pm][1][g0 + 1][u] = aB[1];
          } else {
            lds_piK1[pm][0][g0 + 0][u] = aA[0];
            lds_piK1[pm][0][g0 + 1][u] = aA[1];
            lds_piK1[pm][1][g0 + 0][u] = aB[0];
            lds_piK1[pm][1][g0 + 1][u] = aB[1];
          }
        }
      }
      // Deferred linear head: every 64 intervals, waves 4,5 emit 64 outs
      // each (chunk c=k-66; h2(c+63) landed at interval c+65; writer this
      // interval touches slot (c+64)&127 -- disjoint from read slots).
      if (wid < 6 && k >= 66 && ((k - 66) & 63) == 0) {
        const int c = k - 66;
        const int seq = wid - 4;
        const int m = c + lane;
        const float* r = &lds_h2h[seq][m & (RING - 1)][0];
        const float4* r4 = reinterpret_cast<const float4*>(r);
        const float4* w4 = reinterpret_cast<const float4*>(lds_wlin);
        float o0 = 0.f, o1 = 0.f, o2 = 0.f, o3 = 0.f;
#pragma unroll
        for (int q = 0; q < 12; ++q) {
          float4 rv = r4[q];
          float4 wv = w4[q];
          o0 = fmaf(rv.x, wv.x, o0);
          o1 = fmaf(rv.y, wv.y, o1);
          o2 = fmaf(rv.z, wv.z, o2);
          o3 = fmaf(rv.w, wv.w, o3);
        }
        o0 = fmaf(r[48], lds_wlin[48], o0);
        o1 = fmaf(r[49], lds_wlin[49], o1);
        o2 = fmaf(r[50], lds_wlin[50], o2);
        float o = (o0 + o1) + (o2 + o3) + blin_s;
        out[(s0 + seq) * TT + m] = o;
        if (m == TMAIN - 1) lds_fb[seq] = o;  // feedback seed
      }
    }
    __syncthreads();
  }

  // =============== feedback phase: 3 sub-phases, barriered ==============
  for (int t = TMAIN; t < TT; ++t) {
    float phA[2] = {0.f, 0.f}, phB[2] = {0.f, 0.f};
    // --- A: L1 cell with feedback x; cell waves pre-dot Wh2 @ h2(t-1) ---
    if (wid < 2) {
      float oA, oB;
      if (t == TMAIN) {
        oA = lds_fb[0];
        oB = lds_fb[1];
      } else {
        oA = lds_lin[(t - 1) & 1][0][0] + lds_lin[(t - 1) & 1][0][1] + blin_s;
        oB = lds_lin[(t - 1) & 1][1][0] + lds_lin[(t - 1) & 1][1][1] + blin_s;
        if (lane == 0) {  // buffer future outputs; flushed in epilogue
          if (wid == 0) lds_outbuf[0][t - 1 - TMAIN] = oA;
          else          lds_outbuf[1][t - 1 - TMAIN] = oB;
        }
      }
      float aA[2], aB[2];
#pragma unroll
      for (int g = 0; g < 2; ++g) {
        aA[g] = fmaf(oA, wi1g[g], bias[g]);
        aB[g] = fmaf(oB, wi1g[g], bias[g]);
      }
      dot2x(lds_h1[0][t & 1], lds_h1[1][t & 1], w2f, w50f, aA, aB);
      float pA0 = __shfl_xor(aA[0], 32), pA1 = __shfl_xor(aA[1], 32);
      float pB0 = __shfl_xor(aB[0], 32), pB1 = __shfl_xor(aB[1], 32);
      float giA = half ? pA0 : aA[0], gfA = half ? pA1 : aA[1];
      float ggA = half ? aA[0] : pA0, goA = half ? aA[1] : pA1;
      float giB = half ? pB0 : aB[0], gfB = half ? pB1 : aB[1];
      float ggB = half ? aB[0] : pB0, goB = half ? aB[1] : pB1;
      cA = fast_sigmoid(gfA) * cA + fast_sigmoid(giA) * fast_tanh(ggA);
      cB = fast_sigmoid(gfB) * cB + fast_sigmoid(giB) * fast_tanh(ggB);
      float hA = fast_sigmoid(goA) * fast_tanh(cA);
      float hB = fast_sigmoid(goB) * fast_tanh(cB);
      if (act && half == 0) {
        lds_h1[0][(t + 1) & 1][u] = hA;
        lds_h1[1][(t + 1) & 1][u] = hB;
      }
    } else if (wid < 4) {
      dot2x(&lds_h2h[0][(t - 1) & (RING - 1)][0],
            &lds_h2h[1][(t - 1) & (RING - 1)][0], w2f, w50f, phA, phB);
    }
    __syncthreads();
    // --- B: piK halves from h1(t) ---
    if (wid >= 4) {
      float aA[2], aB[2];
      dotH(&lds_h1[0][(t + 1) & 1][koff], &lds_h1[1][(t + 1) & 1][koff], w2h,
           aA, aB);
      const int pm = t & 1;
      if (act) {
        if (koff == 26) {
          aA[0] += bias[0];
          aA[1] += bias[1];
          aB[0] += bias[0];
          aB[1] += bias[1];
          lds_piK2[pm][0][g0 + 0][u] = aA[0];
          lds_piK2[pm][0][g0 + 1][u] = aA[1];
          lds_piK2[pm][1][g0 + 0][u] = aB[0];
          lds_piK2[pm][1][g0 + 1][u] = aB[1];
        } else {
          lds_piK1[pm][0][g0 + 0][u] = aA[0];
          lds_piK1[pm][0][g0 + 1][u] = aA[1];
          lds_piK1[pm][1][g0 + 0][u] = aB[0];
          lds_piK1[pm][1][g0 + 1][u] = aB[1];
        }
      }
    }
    __syncthreads();
    // --- C: L2 cell + linear head (butterfly on cell waves here) ---
    if (wid >= 2 && wid < 4) {
      const int pm = t & 1;
      float aA[2], aB[2];
      aA[0] = lds_piK1[pm][0][g0 + 0][u] + lds_piK2[pm][0][g0 + 0][u] + phA[0];
      aA[1] = lds_piK1[pm][0][g0 + 1][u] + lds_piK2[pm][0][g0 + 1][u] + phA[1];
      aB[0] = lds_piK1[pm][1][g0 + 0][u] + lds_piK2[pm][1][g0 + 0][u] + phB[0];
      aB[1] = lds_piK1[pm][1][g0 + 1][u] + lds_piK2[pm][1][g0 + 1][u] + phB[1];
      float pA0 = __shfl_xor(aA[0], 32), pA1 = __shfl_xor(aA[1], 32);
      float pB0 = __shfl_xor(aB[0], 32), pB1 = __shfl_xor(aB[1], 32);
      float giA = half ? pA0 : aA[0], gfA = half ? pA1 : aA[1];
      float ggA = half ? aA[0] : pA0, goA = half ? aA[1] : pA1;
      float giB = half ? pB0 : aB[0], gfB = half ? pB1 : aB[1];
      float ggB = half ? aB[0] : pB0, goB = half ? aB[1] : pB1;
      cA = fast_sigmoid(gfA) * cA + fast_sigmoid(giA) * fast_tanh(ggA);
      cB = fast_sigmoid(gfB) * cB + fast_sigmoid(giB) * fast_tanh(ggB);
      float hA = fast_sigmoid(goA) * fast_tanh(cA);
      float hB = fast_sigmoid(goB) * fast_tanh(cB);
      float val = 0.0f;
      if (act) {
        if (half == 0) {
          lds_h2h[0][t & (RING - 1)][u] = hA;
          val = wlin_u * hA;
        } else {
          lds_h2h[1][t & (RING - 1)][u] = hB;
          val = wlin_u * hB;
        }
      }
#pragma unroll
      for (int off = 16; off >= 1; off >>= 1) val += __shfl_xor(val, off);
      if (lane == 0) lds_lin[t & 1][0][wid - 2] = val;
      if (lane == 32) lds_lin[t & 1][1][wid - 2] = val;
    }
    __syncthreads();
  }

  // epilogue: buffer out(TT-1), then flush the 64 future outputs
  if (wid < 2 && lane == 0) {
    float o = lds_lin[(TT - 1) & 1][wid][0] + lds_lin[(TT - 1) & 1][wid][1] +
              blin_s;
    lds_outbuf[wid][63] = o;
  }
  __syncthreads();
  if (wid == 4 || wid == 5) {
    const int seq = wid - 4;
    out[(s0 + seq) * TT + TMAIN + lane] = lds_outbuf[seq][lane];
  }
}

extern "C" void kernel_launch(void* const* d_in, const int* in_sizes, int n_in,
                              void* d_out, int out_size, void* d_ws,
                              size_t ws_size, hipStream_t stream) {
  const float* input = (const float*)d_in[0];
  const float* Wi1 = (const float*)d_in[1];
  const float* Wh1 = (const float*)d_in[2];
  const float* bi1 = (const float*)d_in[3];
  const float* bh1 = (const float*)d_in[4];
  const float* Wi2 = (const float*)d_in[5];
  const float* Wh2 = (const float*)d_in[6];
  const float* bi2 = (const float*)d_in[7];
  const float* bh2 = (const float*)d_in[8];
  const float* Wlin = (const float*)d_in[9];
  const float* blin = (const float*)d_in[10];
  float* out = (float*)d_out;

  const int B = in_sizes[0] / TMAIN;  // 512
  lstm2_persistent<<<B / 2, 512, 0, stream>>>(input, Wi1, Wh1, bi1, bh1, Wi2,
                                              Wh2, bi2, bh2, Wlin, blin, out);
}